// Round 1
// baseline (76.372 us; speedup 1.0000x reference)
//
#include <hip/hip_runtime.h>

#define NMAX 1024
#define BLOCK 256

__global__ __launch_bounds__(BLOCK) void voxel_raster_kernel(
    const float* __restrict__ positions, const float* __restrict__ sizes,
    const float* __restrict__ densities, const float* __restrict__ colors,
    const float* __restrict__ ray_o, const float* __restrict__ ray_d,
    float* __restrict__ out, int N, int B)
{
    const int b   = blockIdx.x;
    const int tid = threadIdx.x;

    __shared__ int cnt;
    __shared__ unsigned long long skey[NMAX];
    __shared__ float sws[NMAX], sdep[NMAX];
    __shared__ float sr[NMAX], sg[NMAX], sb[NMAX];

    if (tid == 0) cnt = 0;
    __syncthreads();

    // per-ray data (broadcast loads, L2-resident)
    const float ox = ray_o[b * 3 + 0], oy = ray_o[b * 3 + 1], oz = ray_o[b * 3 + 2];
    const float dx = ray_d[b * 3 + 0], dy = ray_d[b * 3 + 1], dz = ray_d[b * 3 + 2];
    const float ivx = 1.0f / dx, ivy = 1.0f / dy, ivz = 1.0f / dz;

    // degree-2 real SH basis: [1, y, z, x, xy, yz, 3z^2-1, xz, x^2-y^2]
    float sh[9];
    sh[0] = 1.0f;  sh[1] = dy;      sh[2] = dz;           sh[3] = dx;
    sh[4] = dx*dy; sh[5] = dy*dz;   sh[6] = 3.0f*dz*dz-1.0f;
    sh[7] = dx*dz; sh[8] = dx*dx - dy*dy;

    for (int n = tid; n < N; n += BLOCK) {
        const float half = sizes[n] * 0.5f;
        const float px = positions[n * 3 + 0];
        const float py = positions[n * 3 + 1];
        const float pz = positions[n * 3 + 2];

        float t0 = (px - half - ox) * ivx, t1 = (px + half - ox) * ivx;
        float tn = fminf(t0, t1), tf = fmaxf(t0, t1);
        t0 = (py - half - oy) * ivy; t1 = (py + half - oy) * ivy;
        tn = fmaxf(tn, fminf(t0, t1)); tf = fminf(tf, fmaxf(t0, t1));
        t0 = (pz - half - oz) * ivz; t1 = (pz + half - oz) * ivz;
        tn = fmaxf(tn, fminf(t0, t1)); tf = fminf(tf, fmaxf(t0, t1));

        const bool valid = (tf > tn) && (tf > 0.0f);
        if (!valid) continue;

        // within-voxel alpha compositing: S=8 samples, constant sigma
        const float sigma = expf(densities[n]);
        const float dt    = tf - tn;
        const float alpha = 1.0f - expf(-sigma * dt * 0.125f);
        const float base  = 1.0f - alpha + 1e-8f;
        float pw = 1.0f, ws = 0.0f, dep = 0.0f;
        #pragma unroll
        for (int i = 0; i < 8; i++) {
            const float w  = alpha * pw;
            const float ts = tn + dt * ((float)i * (1.0f / 7.0f));
            ws  += w;
            dep += w * ts;
            pw  *= base;
        }

        // per-channel SH color + sigmoid
        float rgb[3];
        #pragma unroll
        for (int k = 0; k < 3; k++) {
            float acc = 0.0f;
            #pragma unroll
            for (int c = 0; c < 9; c++)
                acc += sh[c] * colors[n * 27 + k * 9 + c];
            rgb[k] = 1.0f / (1.0f + expf(-acc));
        }

        const int slot = atomicAdd(&cnt, 1);
        // sortable key: (flip-transformed tn) << 32 | voxel_idx << 16 | slot
        unsigned u = __float_as_uint(tn);
        u = (u & 0x80000000u) ? ~u : (u | 0x80000000u);
        skey[slot] = ((unsigned long long)u << 32) |
                     ((unsigned long long)(unsigned)n << 16) |
                     (unsigned long long)(unsigned)slot;
        sws[slot]  = ws;
        sdep[slot] = dep;
        sr[slot] = rgb[0]; sg[slot] = rgb[1]; sb[slot] = rgb[2];
    }
    __syncthreads();

    const int m = cnt;
    int P = 1;
    while (P < m) P <<= 1;
    for (int i = m + tid; i < P; i += BLOCK)
        skey[i] = 0xFFFFFFFFFFFFFFFFull;

    if (m > 1) {
        for (int k = 2; k <= P; k <<= 1) {
            for (int j = k >> 1; j > 0; j >>= 1) {
                __syncthreads();
                for (int i = tid; i < P; i += BLOCK) {
                    const int ixj = i ^ j;
                    if (ixj > i) {
                        const unsigned long long a = skey[i];
                        const unsigned long long c = skey[ixj];
                        const bool up = ((i & k) == 0);
                        if ((a > c) == up) { skey[i] = c; skey[ixj] = a; }
                    }
                }
            }
        }
    }
    __syncthreads();

    if (tid == 0) {
        float T = 1.0f, ra = 0.f, ga = 0.f, ba = 0.f, da = 0.f, wa = 0.f;
        for (int i = 0; i < m; i++) {
            if (T < 0.01f) break;          // proc = (T_before >= EARLY_STOP_T)
            const int slot = (int)(skey[i] & 0xFFFFull);
            const float w  = sws[slot];
            const float cw = T * w;
            ra += cw * sr[slot];
            ga += cw * sg[slot];
            ba += cw * sb[slot];
            da += T * sdep[slot];
            wa += cw;
            T *= (1.0f - w);
        }
        out[b * 3 + 0] = ra;
        out[b * 3 + 1] = ga;
        out[b * 3 + 2] = ba;
        out[B * 3 + b] = (m > 0) ? da : 100.0f;   // FAR_PLANE when no hit
        out[B * 4 + b] = wa;
    }
}

extern "C" void kernel_launch(void* const* d_in, const int* in_sizes, int n_in,
                              void* d_out, int out_size, void* d_ws, size_t ws_size,
                              hipStream_t stream) {
    const float* positions = (const float*)d_in[0];
    const float* sizes     = (const float*)d_in[1];
    const float* densities = (const float*)d_in[2];
    const float* colors    = (const float*)d_in[3];
    const float* ray_o     = (const float*)d_in[4];
    const float* ray_d     = (const float*)d_in[5];
    const int N = in_sizes[1];          // 1024 voxels
    const int B = in_sizes[4] / 3;      // 2048 rays

    voxel_raster_kernel<<<B, BLOCK, 0, stream>>>(
        positions, sizes, densities, colors, ray_o, ray_d,
        (float*)d_out, N, B);
}